// Round 11
// baseline (155.198 us; speedup 1.0000x reference)
//
#include <hip/hip_runtime.h>

#define IMG 512
#define NPLANES 48            // 16*3
#define TW 64                 // output tile width
#define TH 16                 // output tile height (R11: halved -> 8 blocks/CU)
#define RD 5
#define KW 11
#define VC (TW + 2*RD)        // 74 columns of vertical sums
#define PRW (2*VC)            // 148 floats = 592B rows (16B-aligned)
#define NTX (IMG/TW)          // 8
#define NTY (IMG/TH)          // 32
#define TPP (NTX*NTY)         // 256
#define NBLOCKS (NPLANES*TPP) // 12288
#define NPIX (16.0f*3.0f*512.0f*512.0f)

typedef float v2f __attribute__((ext_vector_type(2)));

// Packed fp32 (VOP3P). NOTE (R10 model fix): pk ops issue in 4 cyc/wave64 on
// SIMD-32 (157.3 TF peak is the SCALAR rate) — pk saves issue slots, not
// VALU cycles. The (s,d) decomposition's 5ch->4ch FLOP cut is the real win.
__device__ __forceinline__ v2f pk_fma(v2f a, v2f b, v2f c) {
    v2f d;
    asm("v_pk_fma_f32 %0, %1, %2, %3" : "=v"(d) : "v"(a), "v"(b), "v"(c));
    return d;
}
__device__ __forceinline__ v2f pk_mul(v2f a, v2f b) {
    v2f d;
    asm("v_pk_mul_f32 %0, %1, %2" : "=v"(d) : "v"(a), "v"(b));
    return d;
}
// (a+b, a-b) via scalar add/sub; compiler builds the pair for asm consumers.
__device__ __forceinline__ v2f pk_sd(float a, float b) {
    v2f d;
    d.x = a + b;
    d.y = a - b;
    return d;
}

__device__ __forceinline__ float fast_rcp(float d) {
    float r = __builtin_amdgcn_rcpf(d);
    r = r * (2.0f - d * r);   // one Newton step: ~1e-7 rel error
    return r;
}

// (s,d) channel decomposition: s=a+b, d=a-b.
//   mus^2 - mud^2 = 4 mu1 mu2      mus^2 + mud^2 = 2(mu1^2+mu2^2)
//   Vs - Vd       = 4 sigma12      Vs + Vd       = 2(sigma1^2+sigma2^2)
// R11: TH=16 -> LDS 18.9 KB -> 8 blocks/CU = 8 independent phase-streams/SIMD
// to cover the ~900-cycle pass-1 HBM-latency stall (the measured 43% idle).
__global__ __launch_bounds__(256) void ssim_kernel(
    const float* __restrict__ img1, const float* __restrict__ img2,
    float* __restrict__ partial)
{
    __shared__ __align__(16) float vSD[TH][PRW];  // (mus, mud) vertical sums
    __shared__ __align__(16) float vQ [TH][PRW];  // (E[ss], E[dd]) vertical sums
    __shared__ float wsum[4];

    const v2f cw2[KW] = {
        {0.00102838f,0.00102838f}, {0.00759876f,0.00759876f},
        {0.03600077f,0.03600077f}, {0.10936069f,0.10936069f},
        {0.21300553f,0.21300553f}, {0.26601172f,0.26601172f},
        {0.21300553f,0.21300553f}, {0.10936069f,0.10936069f},
        {0.03600077f,0.03600077f}, {0.00759876f,0.00759876f},
        {0.00102838f,0.00102838f}
    };

    const int tid = threadIdx.x;
    const int blk = blockIdx.x;
    const int plane = blk / TPP;
    const int t     = blk % TPP;
    const int ty0 = (t / NTX) * TH;
    const int tx0 = (t % NTX) * TW;
    const float* __restrict__ p1 = img1 + (size_t)plane * IMG * IMG;
    const float* __restrict__ p2 = img2 + (size_t)plane * IMG * IMG;

    // block-uniform: no element touches the image border -> skip all predication
    const bool interior = (tx0 >= RD) && (tx0 + TW + RD <= IMG) &&
                          (ty0 >= RD) && (ty0 + TH + RD <= IMG);

    // ---- pass 1: vertical 11-tap on (s,d) and (s^2,d^2), global -> LDS ----
    // 148 tasks: (col 0..73) x (2 segments of 8 outputs); single round.
    if (tid < VC * 2) {
        const int col = tid % VC;        // storage column
        const int sp  = tid / VC;        // 0..1
        const int gx  = tx0 + col - RD;
        const int r0  = sp * 8;

        float a[18], b[18];
        if (interior) {
            // uniform base + 32-bit offset -> saddr-form loads
            const unsigned off0 = (unsigned)((ty0 + r0 - RD) * IMG + gx);
            #pragma unroll
            for (int k = 0; k < 18; k++) {
                a[k] = p1[off0 + (unsigned)(k * IMG)];
                b[k] = p2[off0 + (unsigned)(k * IMG)];
            }
        } else {
            const bool xok = (gx >= 0) && (gx < IMG);
            #pragma unroll
            for (int k = 0; k < 18; k++) {
                const int gy = ty0 + r0 + k - RD;
                const bool ok = xok && (gy >= 0) && (gy < IMG);
                const int gi = gy * IMG + gx;
                a[k] = ok ? p1[gi] : 0.f;
                b[k] = ok ? p2[gi] : 0.f;
            }
        }

        // packed vertical conv: per tap 2 pk_fma; first tap (d==0) is a
        // pk_mul so no accumulator zero-init movs are ever emitted.
        v2f sSD[8], sQ[8];
        #pragma unroll
        for (int k = 0; k < 18; k++) {
            const v2f sd = pk_sd(a[k], b[k]);    // (a+b, a-b)
            const v2f q  = pk_mul(sd, sd);       // (s^2,  d^2)
            #pragma unroll
            for (int o = 0; o < 8; o++) {
                const int d = k - o;             // tap index, compile-time
                if (d == 0) {
                    sSD[o] = pk_mul(cw2[0], sd);
                    sQ[o]  = pk_mul(cw2[0], q);
                } else if (d > 0 && d < KW) {
                    sSD[o] = pk_fma(cw2[d], sd, sSD[o]);
                    sQ[o]  = pk_fma(cw2[d], q,  sQ[o]);
                }
            }
        }

        #pragma unroll
        for (int o = 0; o < 8; o++) {
            const int r = r0 + o;
            *(v2f*)&vSD[r][2 * col] = sSD[o];
            *(v2f*)&vQ [r][2 * col] = sQ[o];
        }
    }
    __syncthreads();

    // ---- pass 2: horizontal 11-tap (packed) + SSIM; 4 outputs/thread ----
    const float C1 = 1e-4f;
    const float C2 = 9e-4f;
    const v2f NEG1 = {-1.f, -1.f};
    float acc = 0.f;
    {
        const int j = tid & 15;              // group: outputs 4j..4j+3
        const int r = tid >> 4;              // row 0..15

        // pairs 4j .. 4j+13 -> exactly 7 float4 reads per array
        v2f prSD[14], prQ[14];
        {
            const float4* rowp = (const float4*)&vSD[r][0];
            #pragma unroll
            for (int i = 0; i < 7; i++) {
                const float4 q = rowp[2 * j + i];
                prSD[2 * i]     = (v2f){q.x, q.y};
                prSD[2 * i + 1] = (v2f){q.z, q.w};
            }
        }
        {
            const float4* rowp = (const float4*)&vQ[r][0];
            #pragma unroll
            for (int i = 0; i < 7; i++) {
                const float4 q = rowp[2 * j + i];
                prQ[2 * i]     = (v2f){q.x, q.y};
                prQ[2 * i + 1] = (v2f){q.z, q.w};
            }
        }

        #pragma unroll
        for (int o = 0; o < 4; o++) {
            v2f M = pk_mul(cw2[0], prSD[o]);   // (mus, mud)
            v2f X = pk_mul(cw2[0], prQ[o]);    // (E[ss], E[dd])
            #pragma unroll
            for (int d = 1; d < KW; d++) {
                M = pk_fma(cw2[d], prSD[o + d], M);
                X = pk_fma(cw2[d], prQ[o + d], X);
            }
            const v2f M2 = pk_mul(M, M);          // (mus^2, mud^2)
            const v2f V  = pk_fma(M2, NEG1, X);   // (Vs, Vd)
            const float mm = M2.x - M2.y;         // 4 mu1 mu2
            const float mp = M2.x + M2.y;         // 2 (mu1^2 + mu2^2)
            const float vm = V.x - V.y;           // 4 sigma12
            const float vp = V.x + V.y;           // 2 (s1^2 + s2^2)
            const float num = fmaf(0.5f, mm, C1) * fmaf(0.5f, vm, C2);
            const float den = fmaf(0.5f, mp, C1) * fmaf(0.5f, vp, C2);
            acc += num * fast_rcp(den);
        }
    }

    // ---- block reduction ----
    #pragma unroll
    for (int off = 32; off > 0; off >>= 1)
        acc += __shfl_down(acc, off, 64);
    const int lane = tid & 63;
    const int wv_i = tid >> 6;
    if (lane == 0) wsum[wv_i] = acc;
    __syncthreads();
    if (tid == 0)
        partial[blk] = (wsum[0] + wsum[1]) + (wsum[2] + wsum[3]);
}

__global__ __launch_bounds__(256) void ssim_reduce_kernel(
    const float* __restrict__ partial, float* __restrict__ out)
{
    float acc = 0.f;
    for (int i = threadIdx.x; i < NBLOCKS; i += 256)
        acc += partial[i];
    #pragma unroll
    for (int off = 32; off > 0; off >>= 1)
        acc += __shfl_down(acc, off, 64);
    __shared__ float wsum[4];
    const int lane = threadIdx.x & 63;
    const int wv_i = threadIdx.x >> 6;
    if (lane == 0) wsum[wv_i] = acc;
    __syncthreads();
    if (threadIdx.x == 0)
        out[0] = ((wsum[0] + wsum[1]) + (wsum[2] + wsum[3])) * (1.0f / NPIX);
}

extern "C" void kernel_launch(void* const* d_in, const int* in_sizes, int n_in,
                              void* d_out, int out_size, void* d_ws, size_t ws_size,
                              hipStream_t stream) {
    const float* img1 = (const float*)d_in[0];
    const float* img2 = (const float*)d_in[1];
    float* out = (float*)d_out;
    float* partial = (float*)d_ws;   // NBLOCKS floats (48KB) of scratch

    ssim_kernel<<<NBLOCKS, 256, 0, stream>>>(img1, img2, partial);
    ssim_reduce_kernel<<<1, 256, 0, stream>>>(partial, out);
}

// Round 12
// 144.834 us; speedup vs baseline: 1.0716x; 1.0716x over previous
//
#include <hip/hip_runtime.h>

#define IMG 512
#define NPLANES 48            // 16*3
#define TW 64                 // output tile width
#define TH 32                 // output tile height (per pipelined sub-tile)
#define TPAIR 64              // rows per block = two pipelined tiles
#define RD 5
#define KW 11
#define VC (TW + 2*RD)        // 74 columns of vertical sums
#define PRW (2*VC)            // 148 floats = 592B rows (16B-aligned)
#define NTX (IMG/TW)          // 8
#define NTYP (IMG/TPAIR)      // 8 tile-pairs vertically
#define TPP (NTX*NTYP)        // 64
#define NBLOCKS (NPLANES*TPP) // 3072
#define NPIX (16.0f*3.0f*512.0f*512.0f)

typedef float v2f __attribute__((ext_vector_type(2)));

// Packed fp32 (VOP3P). pk ops issue 4 cyc/wave64 (SIMD-32); FLOP-rate-equal
// to scalar — value is issue-slot compression. VOP3P asm operands must be
// 64-bit VGPR pairs (R8 lesson).
__device__ __forceinline__ v2f pk_fma(v2f a, v2f b, v2f c) {
    v2f d;
    asm("v_pk_fma_f32 %0, %1, %2, %3" : "=v"(d) : "v"(a), "v"(b), "v"(c));
    return d;
}
__device__ __forceinline__ v2f pk_mul(v2f a, v2f b) {
    v2f d;
    asm("v_pk_mul_f32 %0, %1, %2" : "=v"(d) : "v"(a), "v"(b));
    return d;
}
__device__ __forceinline__ v2f pk_sd(float a, float b) {
    v2f d;
    d.x = a + b;
    d.y = a - b;
    return d;
}

__device__ __forceinline__ float fast_rcp(float d) {
    float r = __builtin_amdgcn_rcpf(d);
    r = r * (2.0f - d * r);   // one Newton step: ~1e-7 rel error
    return r;
}

// (s,d) channel decomposition (R9) + 16-output pass-1 / 8-output pass-2 (R10)
// + R12: two vertically-stacked tiles per block, software-pipelined:
//   load T0 -> conv T0 -> bar -> ISSUE T1 loads -> pass2 T0 (covers T1 load
//   latency) -> bar -> conv T1 -> bar -> pass2 T1.
// Breaks the all-blocks-in-lock-step load stall (R4/R11: same-phase streams
// never helped; phase-offset work inside the block is the remaining lever).
__global__ __launch_bounds__(256) void ssim_kernel(
    const float* __restrict__ img1, const float* __restrict__ img2,
    float* __restrict__ partial)
{
    __shared__ __align__(16) float vSD[TH][PRW];  // (mus, mud) vertical sums
    __shared__ __align__(16) float vQ [TH][PRW];  // (E[ss], E[dd]) vertical sums
    __shared__ float wsum[4];

    const v2f cw2[KW] = {
        {0.00102838f,0.00102838f}, {0.00759876f,0.00759876f},
        {0.03600077f,0.03600077f}, {0.10936069f,0.10936069f},
        {0.21300553f,0.21300553f}, {0.26601172f,0.26601172f},
        {0.21300553f,0.21300553f}, {0.10936069f,0.10936069f},
        {0.03600077f,0.03600077f}, {0.00759876f,0.00759876f},
        {0.00102838f,0.00102838f}
    };

    const int tid = threadIdx.x;
    const int blk = blockIdx.x;
    const int plane = blk / TPP;
    const int t     = blk % TPP;
    const int ty0 = (t / NTX) * TPAIR;   // first tile's top row
    const int tx0 = (t % NTX) * TW;
    const float* __restrict__ p1 = img1 + (size_t)plane * IMG * IMG;
    const float* __restrict__ p2 = img2 + (size_t)plane * IMG * IMG;

    const bool xint   = (tx0 >= RD) && (tx0 + TW + RD <= IMG);
    const bool p1task = (tid < VC * 2);
    const int col = tid % VC;            // valid when p1task
    const int sp  = tid / VC;            // 0..1
    const int gx  = tx0 + col - RD;

    // ---- tile load: 26 halo rows for 16 outputs, registers only ----
    auto load_tile = [&](int ty, float* a, float* b) {
        if (!p1task) return;
        const int r0 = sp * 16;
        if (xint && (ty >= RD) && (ty + TH + RD <= IMG)) {
            const unsigned off0 = (unsigned)((ty + r0 - RD) * IMG + gx);
            #pragma unroll
            for (int k = 0; k < 26; k++) {
                a[k] = p1[off0 + (unsigned)(k * IMG)];
                b[k] = p2[off0 + (unsigned)(k * IMG)];
            }
        } else {
            const bool xok = (gx >= 0) && (gx < IMG);
            #pragma unroll
            for (int k = 0; k < 26; k++) {
                const int gy = ty + r0 + k - RD;
                const bool ok = xok && (gy >= 0) && (gy < IMG);
                const int gi = gy * IMG + gx;
                a[k] = ok ? p1[gi] : 0.f;
                b[k] = ok ? p2[gi] : 0.f;
            }
        }
    };

    // ---- vertical 11-tap conv on (s,d)/(s^2,d^2), store to LDS ----
    auto conv_store = [&](const float* a, const float* b) {
        if (!p1task) return;
        const int r0 = sp * 16;
        v2f sSD[16], sQ[16];
        #pragma unroll
        for (int k = 0; k < 26; k++) {
            const v2f sd = pk_sd(a[k], b[k]);    // (a+b, a-b)
            const v2f q  = pk_mul(sd, sd);       // (s^2,  d^2)
            #pragma unroll
            for (int o = 0; o < 16; o++) {
                const int d = k - o;             // tap index, compile-time
                if (d == 0) {
                    sSD[o] = pk_mul(cw2[0], sd);
                    sQ[o]  = pk_mul(cw2[0], q);
                } else if (d > 0 && d < KW) {
                    sSD[o] = pk_fma(cw2[d], sd, sSD[o]);
                    sQ[o]  = pk_fma(cw2[d], q,  sQ[o]);
                }
            }
        }
        #pragma unroll
        for (int o = 0; o < 16; o++) {
            const int r = r0 + o;
            *(v2f*)&vSD[r][2 * col] = sSD[o];
            *(v2f*)&vQ [r][2 * col] = sQ[o];
        }
    };

    // ---- horizontal 11-tap + SSIM; 8 outputs/thread, adds into acc ----
    const float C1 = 1e-4f;
    const float C2 = 9e-4f;
    const v2f NEG1 = {-1.f, -1.f};
    auto pass2 = [&](float& accr) {
        const int j = tid & 7;               // group: outputs 8j..8j+7
        const int r = tid >> 3;              // row 0..31
        v2f prSD[18], prQ[18];
        {
            const float4* rowp = (const float4*)&vSD[r][0];
            #pragma unroll
            for (int i = 0; i < 9; i++) {
                const float4 q = rowp[4 * j + i];
                prSD[2 * i]     = (v2f){q.x, q.y};
                prSD[2 * i + 1] = (v2f){q.z, q.w};
            }
        }
        {
            const float4* rowp = (const float4*)&vQ[r][0];
            #pragma unroll
            for (int i = 0; i < 9; i++) {
                const float4 q = rowp[4 * j + i];
                prQ[2 * i]     = (v2f){q.x, q.y};
                prQ[2 * i + 1] = (v2f){q.z, q.w};
            }
        }
        #pragma unroll
        for (int o = 0; o < 8; o++) {
            v2f M = pk_mul(cw2[0], prSD[o]);   // (mus, mud)
            v2f X = pk_mul(cw2[0], prQ[o]);    // (E[ss], E[dd])
            #pragma unroll
            for (int d = 1; d < KW; d++) {
                M = pk_fma(cw2[d], prSD[o + d], M);
                X = pk_fma(cw2[d], prQ[o + d], X);
            }
            const v2f M2 = pk_mul(M, M);          // (mus^2, mud^2)
            const v2f V  = pk_fma(M2, NEG1, X);   // (Vs, Vd)
            const float mm = M2.x - M2.y;         // 4 mu1 mu2
            const float mp = M2.x + M2.y;         // 2 (mu1^2 + mu2^2)
            const float vm = V.x - V.y;           // 4 sigma12
            const float vp = V.x + V.y;           // 2 (s1^2 + s2^2)
            const float num = fmaf(0.5f, mm, C1) * fmaf(0.5f, vm, C2);
            const float den = fmaf(0.5f, mp, C1) * fmaf(0.5f, vp, C2);
            accr += num * fast_rcp(den);
        }
    };

    // ---- pipelined schedule over the two tiles ----
    float a0[26], b0[26], a1[26], b1[26];
    float acc = 0.f;

    load_tile(ty0, a0, b0);                  // T0 loads
    conv_store(a0, b0);                      // T0 vertical conv -> LDS
    __syncthreads();
    load_tile(ty0 + TH, a1, b1);             // ISSUE T1 loads (waitcnt sinks
                                             // to conv_store(a1,b1) below)
    pass2(acc);                              // T0 horizontal+SSIM covers latency
    __syncthreads();                         // LDS reads done before overwrite
    conv_store(a1, b1);                      // T1 vertical conv -> LDS
    __syncthreads();
    pass2(acc);                              // T1 horizontal+SSIM

    // ---- block reduction ----
    #pragma unroll
    for (int off = 32; off > 0; off >>= 1)
        acc += __shfl_down(acc, off, 64);
    const int lane = tid & 63;
    const int wv_i = tid >> 6;
    if (lane == 0) wsum[wv_i] = acc;
    __syncthreads();
    if (tid == 0)
        partial[blk] = (wsum[0] + wsum[1]) + (wsum[2] + wsum[3]);
}

__global__ __launch_bounds__(256) void ssim_reduce_kernel(
    const float* __restrict__ partial, float* __restrict__ out)
{
    float acc = 0.f;
    for (int i = threadIdx.x; i < NBLOCKS; i += 256)
        acc += partial[i];
    #pragma unroll
    for (int off = 32; off > 0; off >>= 1)
        acc += __shfl_down(acc, off, 64);
    __shared__ float wsum[4];
    const int lane = threadIdx.x & 63;
    const int wv_i = threadIdx.x >> 6;
    if (lane == 0) wsum[wv_i] = acc;
    __syncthreads();
    if (threadIdx.x == 0)
        out[0] = ((wsum[0] + wsum[1]) + (wsum[2] + wsum[3])) * (1.0f / NPIX);
}

extern "C" void kernel_launch(void* const* d_in, const int* in_sizes, int n_in,
                              void* d_out, int out_size, void* d_ws, size_t ws_size,
                              hipStream_t stream) {
    const float* img1 = (const float*)d_in[0];
    const float* img2 = (const float*)d_in[1];
    float* out = (float*)d_out;
    float* partial = (float*)d_ws;   // NBLOCKS floats of scratch

    ssim_kernel<<<NBLOCKS, 256, 0, stream>>>(img1, img2, partial);
    ssim_reduce_kernel<<<1, 256, 0, stream>>>(partial, out);
}